// Round 6
// baseline (528.110 us; speedup 1.0000x reference)
//
#include <hip/hip_runtime.h>
#include <hip/hip_bf16.h>
#include <stdint.h>

// Problem constants (AdaLoRALinear): out = x @ (W + 2*(P*Lambda*mask)@Q)^T
// Pipeline:
//   1) prep_all : x->Xb cast + build_weff (verbatim round-5, passing)
//   2) gemm_xwt : out = Xb @ Wb^T. Round-2/4 schedule (best measured), MFMA
//                 shape switched 16x16x32 -> 32x32x16 (m119: +15% pipe rate,
//                 -25% ds_read traffic, half the MFMA instruction count).
#define M_TOK 8192   // batch tokens
#define NF    4096   // OUT_F
#define KF    4096   // IN_F
#define RANK  64

typedef __attribute__((ext_vector_type(8))) short short8;     // 8 x bf16 (4 VGPRs)
typedef __attribute__((ext_vector_type(16))) float floatx16;  // 32x32 MFMA acc

typedef const uint32_t __attribute__((address_space(1)))* gp1_t;
typedef uint32_t __attribute__((address_space(3)))* lp3_t;

__device__ __forceinline__ void load_lds16(const void* g, void* l) {
  // async global->LDS, 16 B per lane; LDS dest must be uniform_base + lane*16
  __builtin_amdgcn_global_load_lds((gp1_t)g, (lp3_t)l, 16, 0, 0);
}

// ---- Kernel 1: prep_all (verbatim round-5, passing) -------------------------
// blocks [0, CASTX_BLOCKS)          : Xb = bf16(x), 8 elems/thread
// blocks [CASTX_BLOCKS, +4096)      : Wb = bf16(W + 2*(P*lam*mask)@Q), 64x64 tile
#define CASTX_BLOCKS ((M_TOK * KF) / (256 * 8))   // 16384
__global__ __launch_bounds__(256) void prep_all(
    const float* __restrict__ x, const float* __restrict__ W,
    const float* __restrict__ P, const float* __restrict__ Lam,
    const float* __restrict__ Q, const unsigned char* __restrict__ mask,
    __hip_bfloat16* __restrict__ Xb, __hip_bfloat16* __restrict__ Wb) {
  __shared__ float lam[RANK];
  __shared__ float plT[RANK][68];  // [r][n_local], padded vs bank conflicts
  __shared__ float Qs[RANK][68];   // [r][k_local]

  const int bid = blockIdx.x;
  const int t = threadIdx.x;

  if (bid < CASTX_BLOCKS) {
    size_t i = ((size_t)bid * 256 + t) * 8;
    float4 a = *(const float4*)(x + i);
    float4 b = *(const float4*)(x + i + 4);
    union { __hip_bfloat16 h[8]; uint4 u; } pk;
    pk.h[0] = __float2bfloat16(a.x); pk.h[1] = __float2bfloat16(a.y);
    pk.h[2] = __float2bfloat16(a.z); pk.h[3] = __float2bfloat16(a.w);
    pk.h[4] = __float2bfloat16(b.x); pk.h[5] = __float2bfloat16(b.y);
    pk.h[6] = __float2bfloat16(b.z); pk.h[7] = __float2bfloat16(b.w);
    *(uint4*)(Xb + i) = pk.u;
    return;
  }

  const int idx = bid - CASTX_BLOCKS;
  const int n0 = (idx >> 6) * 64;
  const int k0 = (idx & 63) * 64;

  if (t < RANK) lam[t] = 2.0f * Lam[t] * (mask[t] ? 1.0f : 0.0f);
  __syncthreads();

  {
    const int nl = t & 63;
    const int rg = (t >> 6) * 16;
    const float* p = P + (size_t)(n0 + nl) * RANK + rg;
#pragma unroll
    for (int j = 0; j < 16; j += 4) {
      float4 v = *(const float4*)(p + j);
      plT[rg + j + 0][nl] = v.x * lam[rg + j + 0];
      plT[rg + j + 1][nl] = v.y * lam[rg + j + 1];
      plT[rg + j + 2][nl] = v.z * lam[rg + j + 2];
      plT[rg + j + 3][nl] = v.w * lam[rg + j + 3];
    }
    const int r = t >> 2;
    const int kc = (t & 3) * 16;
    const float* q = Q + (size_t)r * KF + k0 + kc;
#pragma unroll
    for (int j = 0; j < 16; j += 4) {
      float4 v = *(const float4*)(q + j);
      Qs[r][kc + j + 0] = v.x;
      Qs[r][kc + j + 1] = v.y;
      Qs[r][kc + j + 2] = v.z;
      Qs[r][kc + j + 3] = v.w;
    }
  }
  __syncthreads();

  const int tn4 = t >> 4;
  const int tk4 = t & 15;
  float accv[4][4];
#pragma unroll
  for (int i = 0; i < 4; i++) {
    float4 w = *(const float4*)(W + (size_t)(n0 + tn4 * 4 + i) * KF + k0 + tk4 * 4);
    accv[i][0] = w.x; accv[i][1] = w.y; accv[i][2] = w.z; accv[i][3] = w.w;
  }
#pragma unroll 8
  for (int r = 0; r < RANK; r++) {
    float4 p4 = *(const float4*)&plT[r][tn4 * 4];
    float4 q4 = *(const float4*)&Qs[r][tk4 * 4];
#define ROWFMA(i, pi)                                                  \
    accv[i][0] += (pi) * q4.x; accv[i][1] += (pi) * q4.y;              \
    accv[i][2] += (pi) * q4.z; accv[i][3] += (pi) * q4.w;
    ROWFMA(0, p4.x) ROWFMA(1, p4.y) ROWFMA(2, p4.z) ROWFMA(3, p4.w)
#undef ROWFMA
  }
#pragma unroll
  for (int i = 0; i < 4; i++) {
    union { __hip_bfloat16 h[4]; uint2 u; } pk;
    pk.h[0] = __float2bfloat16(accv[i][0]);
    pk.h[1] = __float2bfloat16(accv[i][1]);
    pk.h[2] = __float2bfloat16(accv[i][2]);
    pk.h[3] = __float2bfloat16(accv[i][3]);
    *(uint2*)(Wb + (size_t)(n0 + tn4 * 4 + i) * KF + k0 + tk4 * 4) = pk.u;
  }
}

// ---- Kernel 2: C[m][n] = sum_k A[m][k]*B[n][k]; A,B bf16 row-major, C fp32.
//
// 256x256 tile, BK=64, 512 threads (8 waves, 2Mx4N), per-wave 128x64 output.
// MFMA shape: 32x32x16 bf16. Per wave per K-tile: mi 0..3 (4x32 rows),
// nj 0..1 (2x32 cols), ks 0..3 (4x16 k) = 32 MFMAs (8 per phase).
//
// Fragment maps (A/B: exact analog of the harness-proven 16x16x32 mapping;
// C/D: guide-verified m74/m101):
//   A (mi,ks): lane l -> row = mi*32 + (l&31), k = ks*16 + (l>>5)*8 + e
//   B (nj,ks): lane l -> col = nj*32 + (l&31), same k
//   C/D reg r: col = lane&31, row = (r&3) + 8*(r>>2) + 4*(lane>>5)
//
// LDS physical layout UNCHANGED (writer side byte-identical to rounds 0-5):
// 2 panels (k-halves) of 256 rows x 64 B per slot; logical 16B chunk c of
// row r at physical chunk (c+(r>>1))&3. Reader chunk for (ks,lane):
//   logical c = (ks&1)*2 + (lane>>5), panel = ks>>1,
//   physical pc[ks] = ((ks&1)*2 + (lane>>5) + (((lane&31)>>1)&3)) & 3
// (all row-base terms wm*128/wn*64/mi*32/nj*32 are =0 mod 4 after >>1).
// Conflict audit: granule g = (4*row + pc) mod 8 -> each 16B granule hit by
// exactly 8 of 64 lanes -> uniform, conflict-free (same property as before).
//
// Schedule/ledgers byte-identical to round-2/4 (best measured, passing):
//   ph0: +4 ds -> 16, LGK(4); ph1: +4 -> 8, LGK(4); ph2: +4 -> 8, LGK(4),
//   vmcnt(2); ph3: +12 -> 16, LGK(12).
//   STAGE_A(t+1) ph0/ph1 -> slot^1; STAGE_B(t+2) ph2/ph3 -> cur B slot.
#define BM 256
#define BN 256
#define BK 64
#define NT (KF / BK)   // 64
#define ASL 16384      // elements per K-tile slot (256*64)

#define SB0 __builtin_amdgcn_sched_barrier(0)
#define BARSYNC do { SB0; __builtin_amdgcn_s_barrier(); } while (0)
#define LGK(n) do { asm volatile("s_waitcnt lgkmcnt(" #n ")" ::: "memory"); SB0; } while (0)

__device__ __forceinline__ void read_a32(short8 (&afr)[4],
                                         const __hip_bfloat16* Asl,
                                         int row, const int (&pc)[4]) {
#pragma unroll
  for (int ks = 0; ks < 4; ++ks)
    afr[ks] = *(const short8*)(Asl + (ks >> 1) * 8192 + row * 32 + pc[ks] * 8);
}

__device__ __forceinline__ void read_b32(short8 (&bfr)[2][4],
                                         const __hip_bfloat16* Bsl,
                                         int row, const int (&pc)[4]) {
#pragma unroll
  for (int nj = 0; nj < 2; ++nj)
#pragma unroll
    for (int ks = 0; ks < 4; ++ks)
      bfr[nj][ks] = *(const short8*)(Bsl + (ks >> 1) * 8192 + (row + nj * 32) * 32 + pc[ks] * 8);
}

template <int MI>
__device__ __forceinline__ void mfma8(floatx16 (&acc)[4][2],
                                      const short8 (&afr)[4],
                                      const short8 (&bfr)[2][4]) {
#pragma unroll
  for (int ks = 0; ks < 4; ++ks)
#pragma unroll
    for (int nj = 0; nj < 2; ++nj)
      acc[MI][nj] = __builtin_amdgcn_mfma_f32_32x32x16_bf16(
          afr[ks], bfr[nj][ks], acc[MI][nj], 0, 0, 0);
}

__global__ __launch_bounds__(512, 2) void gemm_xwt(
    const __hip_bfloat16* __restrict__ A,   // [M_TOK][KF]
    const __hip_bfloat16* __restrict__ B,   // [NF][KF]  (= Wb, row = n)
    float* __restrict__ C) {                // [M_TOK][NF]
  extern __shared__ __hip_bfloat16 lds[];
  __hip_bfloat16* As = lds;            // 2 slots x 16384 elems
  __hip_bfloat16* Bs = lds + 2 * ASL;  // 2 slots x 16384 elems
  const __hip_bfloat16* As0 = As;
  const __hip_bfloat16* As1 = As + ASL;
  const __hip_bfloat16* Bs0 = Bs;
  const __hip_bfloat16* Bs1 = Bs + ASL;

  const int t = threadIdx.x;       // 0..511
  const int lane = t & 63;
  const int wave = t >> 6;         // 0..7
  const int wm = wave >> 2;        // 0..1 : M half (128 rows)
  const int wn = wave & 3;         // 0..3 : N quarter (64 cols)
  const int l31 = lane & 31;
  const int lhi = lane >> 5;       // 0/1 : k-half within fragment

  // physical chunk per ks (swizzle-resolved, row-base independent)
  int pc[4];
#pragma unroll
  for (int ks = 0; ks < 4; ++ks)
    pc[ks] = ((ks & 1) * 2 + lhi + ((l31 >> 1) & 3)) & 3;

  // XCD-bijective block swizzle: 512 wgs, 8 XCDs, 64 contiguous work/XCD.
  const int bid = blockIdx.x;
  const int wk = (bid & 7) * 64 + (bid >> 3);
  const int bm = wk >> 4;   // 0..31
  const int bn = wk & 15;   // 0..15

  // staging: thread t covers within-panel row (t>>2)(+h*128), global chunk c
  const int c = ((t & 3) - ((t >> 3) & 3)) & 3;
  const __hip_bfloat16* a_src = A + (size_t)(bm * BM + (t >> 2)) * KF + c * 8;
  const __hip_bfloat16* b_src = B + (size_t)(bn * BN + (t >> 2)) * KF + c * 8;
  __hip_bfloat16* a_dst = As + t * 8;
  __hip_bfloat16* b_dst = Bs + t * 8;

#define STAGE_A(kt_, slot_, h_)                                                        \
  do {                                                                                 \
    const __hip_bfloat16* s_ = a_src + ((kt_) & (NT - 1)) * BK + (size_t)(h_) * 128 * KF; \
    __hip_bfloat16* d_ = a_dst + (slot_) * ASL + (h_) * 4096;                          \
    load_lds16(s_, d_);                /* ks=0 panel */                                \
    load_lds16(s_ + 32, d_ + 8192);    /* ks=1 panel */                                \
  } while (0)
#define STAGE_B(kt_, slot_, h_)                                                        \
  do {                                                                                 \
    const __hip_bfloat16* s_ = b_src + ((kt_) & (NT - 1)) * BK + (size_t)(h_) * 128 * KF; \
    __hip_bfloat16* d_ = b_dst + (slot_) * ASL + (h_) * 4096;                          \
    load_lds16(s_, d_);                                                                \
    load_lds16(s_ + 32, d_ + 8192);                                                    \
  } while (0)

  floatx16 acc[4][2] = {};
  short8 bE[2][4], bO[2][4];   // B frags, even/odd tile (2 nj x 4 ks)
  short8 aX[4], aY[4];         // A frags ping-pong (one mi x 4 ks)

  const int rowA = wm * 128 + l31;   // + mi*32 per phase
  const int rowB = wn * 64 + l31;    // + nj*32 inside read_b32

  // prologue: A(0),B(0) must land; B(1) may fly. A(1) staged in tile 0.
  STAGE_A(0, 0, 0); STAGE_A(0, 0, 1);
  STAGE_B(0, 0, 0); STAGE_B(0, 0, 1);
  STAGE_B(1, 1, 0); STAGE_B(1, 1, 1);
  asm volatile("s_waitcnt vmcnt(4)" ::: "memory");   // A(0),B(0) landed
  __builtin_amdgcn_s_barrier();
  read_b32(bE, Bs0, rowB, pc);              // 8 reads  (tile 0 B)
  read_a32(aX, As0, rowA + 0 * 32, pc);     // 4 reads  (tile 0 A mi0) -> 12 out

  for (int kt = 0; kt < NT; kt += 2) {
    // ================= tile e = kt (slot 0) =================
    // ph0
    read_a32(aY, As0, rowA + 1 * 32, pc);
    STAGE_A(kt + 1, 1, 0);
    BARSYNC; LGK(4);
    __builtin_amdgcn_s_setprio(1); mfma8<0>(acc, aX, bE); __builtin_amdgcn_s_setprio(0);
    BARSYNC;
    // ph1
    read_a32(aX, As0, rowA + 2 * 32, pc);
    STAGE_A(kt + 1, 1, 1);
    BARSYNC; LGK(4);
    __builtin_amdgcn_s_setprio(1); mfma8<1>(acc, aY, bE); __builtin_amdgcn_s_setprio(0);
    BARSYNC;
    // ph2  (vmcnt(2): retire A(e+1),B(e+1); keep B(e+2)h0 flying)
    read_a32(aY, As0, rowA + 3 * 32, pc);
    STAGE_B(kt + 2, 0, 0);
    BARSYNC; LGK(4);
    __builtin_amdgcn_s_setprio(1); mfma8<2>(acc, aX, bE); __builtin_amdgcn_s_setprio(0);
    SB0;
    asm volatile("s_waitcnt vmcnt(2)" ::: "memory");
    __builtin_amdgcn_s_barrier();
    // ph3  (pre-read next tile's B + A mi0 from slot 1: landed above)
    read_b32(bO, Bs1, rowB, pc);
    read_a32(aX, As1, rowA + 0 * 32, pc);
    STAGE_B(kt + 2, 0, 1);
    BARSYNC; LGK(12);
    __builtin_amdgcn_s_setprio(1); mfma8<3>(acc, aY, bE); __builtin_amdgcn_s_setprio(0);
    BARSYNC;

    // ================= tile o = kt+1 (slot 1) =================
    // ph0
    read_a32(aY, As1, rowA + 1 * 32, pc);
    STAGE_A(kt + 2, 0, 0);
    BARSYNC; LGK(4);
    __builtin_amdgcn_s_setprio(1); mfma8<0>(acc, aX, bO); __builtin_amdgcn_s_setprio(0);
    BARSYNC;
    // ph1
    read_a32(aX, As1, rowA + 2 * 32, pc);
    STAGE_A(kt + 2, 0, 1);
    BARSYNC; LGK(4);
    __builtin_amdgcn_s_setprio(1); mfma8<1>(acc, aY, bO); __builtin_amdgcn_s_setprio(0);
    BARSYNC;
    // ph2
    read_a32(aY, As1, rowA + 3 * 32, pc);
    STAGE_B(kt + 3, 1, 0);
    BARSYNC; LGK(4);
    __builtin_amdgcn_s_setprio(1); mfma8<2>(acc, aX, bO); __builtin_amdgcn_s_setprio(0);
    SB0;
    asm volatile("s_waitcnt vmcnt(2)" ::: "memory");
    __builtin_amdgcn_s_barrier();
    // ph3
    read_b32(bE, Bs0, rowB, pc);
    read_a32(aX, As0, rowA + 0 * 32, pc);
    STAGE_B(kt + 3, 1, 1);
    BARSYNC; LGK(12);
    __builtin_amdgcn_s_setprio(1); mfma8<3>(acc, aY, bO); __builtin_amdgcn_s_setprio(0);
    BARSYNC;
  }

#undef STAGE_A
#undef STAGE_B

  // epilogue: 32x32 D mapping col=lane&31, row=(r&3)+8*(r>>2)+4*(lane>>5)
  const int col0 = bn * BN + wn * 64 + l31;
  const int row0 = bm * BM + wm * 128 + 4 * lhi;
#pragma unroll
  for (int mi = 0; mi < 4; ++mi)
#pragma unroll
    for (int nj = 0; nj < 2; ++nj)
#pragma unroll
      for (int r = 0; r < 16; ++r)
        C[(size_t)(row0 + mi * 32 + (r & 3) + 8 * (r >> 2)) * NF +
          (col0 + nj * 32)] = acc[mi][nj][r];
}

extern "C" void kernel_launch(void* const* d_in, const int* in_sizes, int n_in,
                              void* d_out, int out_size, void* d_ws, size_t ws_size,
                              hipStream_t stream) {
  const float* x      = (const float*)d_in[0];  // [8192][4096]
  const float* weight = (const float*)d_in[1];  // [4096][4096]
  const float* P      = (const float*)d_in[2];  // [4096][64]
  const float* Lam    = (const float*)d_in[3];  // [64]
  const float* Q      = (const float*)d_in[4];  // [64][4096]
  const unsigned char* mask = (const unsigned char*)d_in[5];  // [64] bool8
  float* out = (float*)d_out;

  __hip_bfloat16* Xb = (__hip_bfloat16*)d_ws;                         // 64 MB
  __hip_bfloat16* Wb = (__hip_bfloat16*)((char*)d_ws + (size_t)M_TOK * KF * 2);  // 32 MB

  static int smem_set = 0;
  if (!smem_set) {
    hipFuncSetAttribute((const void*)gemm_xwt,
                        hipFuncAttributeMaxDynamicSharedMemorySize, 131072);
    smem_set = 1;
  }

  // 1) Xb cast + W_eff build (one launch, block-range split)
  prep_all<<<CASTX_BLOCKS + (NF / 64) * (KF / 64), 256, 0, stream>>>(
      x, weight, P, Lam, Q, mask, Xb, Wb);
  // 2) out = Xb @ Wb^T   (512 blocks = 32 bm x 16 bn, XCD-swizzled)
  gemm_xwt<<<dim3((M_TOK / BM) * (NF / BN)), 512, 131072, stream>>>(Xb, Wb, out);
}